// Round 1
// baseline (419.598 us; speedup 1.0000x reference)
//
#include <hip/hip_runtime.h>
#include <stdint.h>

#define TWF 0.2f
#define PI_F 3.14159265358979f

typedef __attribute__((ext_vector_type(8))) short short8;
typedef __attribute__((ext_vector_type(4))) float floatx4;

__device__ __forceinline__ short f2bf(float f){
  unsigned u = __float_as_uint(f);
  u += 0x7fff + ((u >> 16) & 1);           // round-to-nearest-even
  return (short)(u >> 16);
}
__device__ __forceinline__ float bf2f(short s){
  return __uint_as_float(((unsigned)(unsigned short)s) << 16);
}
__device__ __forceinline__ float fast_tanh(float x){
  x = fminf(fmaxf(x, -15.f), 15.f);
  float e = __expf(2.f * x);
  return (e - 1.f) / (e + 1.f);
}
// swizzled LDS index (in shorts) for h[m][j], m in [0,64), j in [0,256)
// 16B chunk (j>>3) xor'd with (m&7) -> conflict-free b128 A-frag reads
__device__ __forceinline__ int swz(int m, int j){
  return m * 256 + ((((j >> 3) ^ (m & 7)) << 3) | (j & 7));
}

// Convert W1/W2 (f32 [16][256][256]) to bf16 in B-fragment lane order:
// dst[mat][k][ks][jt][lane][8], element = W[k][ks*32+(lane>>4)*8+jj][jt*16+(lane&15)]
__global__ __launch_bounds__(256) void prep_weights(const float* __restrict__ W1,
                                                    const float* __restrict__ W2,
                                                    short* __restrict__ dst){
  int gid = blockIdx.x * 256 + threadIdx.x;   // 2*16*8*16*64 = 262144 total
  int lane = gid & 63; int rest = gid >> 6;
  int jt = rest & 15; rest >>= 4;
  int ks = rest & 7;  rest >>= 3;
  int k  = rest & 15; int mat = rest >> 4;
  const float* W = mat ? W2 : W1;
  int j   = jt * 16 + (lane & 15);
  int kk0 = ks * 32 + (lane >> 4) * 8;
  short8 v;
  #pragma unroll
  for (int jj = 0; jj < 8; jj++)
    v[jj] = f2bf(W[k * 65536 + (kk0 + jj) * 256 + j]);
  *(short8*)(dst + (size_t)gid * 8) = v;
}

__global__ __launch_bounds__(256) void fbpinn_main(
    const float* __restrict__ x,  const float* __restrict__ W0, const float* __restrict__ b0,
    const float* __restrict__ b1, const float* __restrict__ b2,
    const float* __restrict__ W3, const float* __restrict__ b3,
    const float* __restrict__ xmins, const float* __restrict__ xmaxs,
    const short* __restrict__ wsw, float* __restrict__ out)
{
  __shared__ short lds_h[64 * 256];   // 32 KB, swizzled bf16 h tile
  __shared__ float s_xn[64 * 2];
  __shared__ float s_win[64];
  __shared__ float s_w3[256];

  const int t    = threadIdx.x;
  const int k    = blockIdx.y;
  const int m0   = blockIdx.x * 64;
  const int lane = t & 63;
  const int wave = t >> 6;
  const int col  = lane & 15;
  const int quad = lane >> 4;

  // ---- stage 1: window weights (all 16 k for the denominator), xn, stage W3 ----
  s_w3[t] = W3[k * 256 + t];
  if (t < 64){
    float px = x[(m0 + t) * 2 + 0], py = x[(m0 + t) * 2 + 1];
    float sum = 0.f, mine = 0.f;
    #pragma unroll
    for (int k2 = 0; k2 < 16; k2++){
      float wr = 1.f;
      #pragma unroll
      for (int d = 0; d < 2; d++){
        float xv = d ? py : px;
        float mn = xmins[k2 * 2 + d], mx = xmaxs[k2 * 2 + d];
        float tl = fminf(fmaxf((xv - (mn - TWF)) * (1.f / (2.f * TWF)), 0.f), 1.f);
        float tr = fminf(fmaxf(((mx + TWF) - xv) * (1.f / (2.f * TWF)), 0.f), 1.f);
        wr *= 0.25f * (1.f - __cosf(PI_F * tl)) * (1.f - __cosf(PI_F * tr));
      }
      sum += wr;
      if (k2 == k) mine = wr;
    }
    s_win[t] = mine / (sum + 1e-9f);
    float cx = (xmins[k * 2 + 0] + xmaxs[k * 2 + 0]) * 0.5f;
    float cy = (xmins[k * 2 + 1] + xmaxs[k * 2 + 1]) * 0.5f;
    float sx = fmaxf((xmaxs[k * 2 + 0] - xmins[k * 2 + 0]) * 0.5f, 1e-9f);
    float sy = fmaxf((xmaxs[k * 2 + 1] - xmins[k * 2 + 1]) * 0.5f, 1e-9f);
    s_xn[t * 2 + 0] = (px - cx) / sx;
    s_xn[t * 2 + 1] = (py - cy) / sy;
  }
  __syncthreads();

  // ---- layer 0 (D=2 -> 256), f32 vector, thread t owns hidden unit j=t ----
  {
    float w00 = W0[k * 512 + t];
    float w01 = W0[k * 512 + 256 + t];
    float bb  = b0[k * 256 + t];
    #pragma unroll 4
    for (int m = 0; m < 64; m++){
      float v = fast_tanh(fmaf(s_xn[m * 2], w00, fmaf(s_xn[m * 2 + 1], w01, bb)));
      lds_h[swz(m, t)] = f2bf(v);
    }
  }
  __syncthreads();

  // ---- layers 1,2: 64x256x256 bf16 MFMA; wave owns j-range [wave*64, wave*64+64) ----
  #pragma unroll 1
  for (int layer = 0; layer < 2; layer++){
    const short8* wp = (const short8*)(wsw + (size_t)layer * 1048576);
    const float*  bp = layer ? b2 : b1;
    floatx4 acc[4][4];
    #pragma unroll
    for (int a = 0; a < 4; a++)
      #pragma unroll
      for (int b = 0; b < 4; b++)
        acc[a][b] = (floatx4){0.f, 0.f, 0.f, 0.f};

    #pragma unroll 2
    for (int ks = 0; ks < 8; ks++){
      short8 bfr[4], afr[4];
      #pragma unroll
      for (int jtl = 0; jtl < 4; jtl++)
        bfr[jtl] = wp[((size_t)(k * 8 + ks) * 16 + (wave * 4 + jtl)) * 64 + lane];
      #pragma unroll
      for (int mt = 0; mt < 4; mt++){
        int m   = mt * 16 + col;                 // A: m = lane&15
        int pos = (ks * 4 + quad) ^ (m & 7);     // A: k-chunk = quad
        afr[mt] = *(const short8*)&lds_h[m * 256 + pos * 8];
      }
      #pragma unroll
      for (int mt = 0; mt < 4; mt++)
        #pragma unroll
        for (int jtl = 0; jtl < 4; jtl++)
          acc[mt][jtl] = __builtin_amdgcn_mfma_f32_16x16x32_bf16(afr[mt], bfr[jtl], acc[mt][jtl], 0, 0, 0);
    }
    __syncthreads();   // all reads of h done before overwrite

    #pragma unroll
    for (int jtl = 0; jtl < 4; jtl++){
      int j = (wave * 4 + jtl) * 16 + col;       // D: col = lane&15
      float bb = bp[k * 256 + j];
      #pragma unroll
      for (int mt = 0; mt < 4; mt++){
        #pragma unroll
        for (int r = 0; r < 4; r++){
          int m = mt * 16 + quad * 4 + r;        // D: row = quad*4 + r
          float v = fast_tanh(acc[mt][jtl][r] + bb);
          lds_h[swz(m, j)] = f2bf(v);
        }
      }
    }
    __syncthreads();
  }

  // ---- layer 3 (256 -> 1) + window-weighted combine ----
  {
    int m = t >> 2, q = t & 3;     // 4 threads per point
    float dot = 0.f;
    #pragma unroll
    for (int cc = 0; cc < 8; cc++){
      int ci  = q * 8 + cc;
      int pos = ci ^ (m & 7);
      short8 hv = *(const short8*)&lds_h[m * 256 + pos * 8];
      #pragma unroll
      for (int jj = 0; jj < 8; jj++)
        dot = fmaf(bf2f(hv[jj]), s_w3[ci * 8 + jj], dot);
    }
    dot += __shfl_xor(dot, 1);
    dot += __shfl_xor(dot, 2);
    if (q == 0)
      atomicAdd(&out[m0 + m], s_win[m] * (dot + b3[k]));
  }
}

extern "C" void kernel_launch(void* const* d_in, const int* in_sizes, int n_in,
                              void* d_out, int out_size, void* d_ws, size_t ws_size,
                              hipStream_t stream){
  const float* x     = (const float*)d_in[0];
  const float* W0    = (const float*)d_in[1];
  const float* b0    = (const float*)d_in[2];
  const float* W1    = (const float*)d_in[3];
  const float* b1    = (const float*)d_in[4];
  const float* W2    = (const float*)d_in[5];
  const float* b2    = (const float*)d_in[6];
  const float* W3    = (const float*)d_in[7];
  const float* b3    = (const float*)d_in[8];
  const float* xmins = (const float*)d_in[9];
  const float* xmaxs = (const float*)d_in[10];
  float* out = (float*)d_out;
  short* wsw = (short*)d_ws;   // needs 4 MB

  hipMemsetAsync(d_out, 0, (size_t)out_size * sizeof(float), stream);
  prep_weights<<<1024, 256, 0, stream>>>(W1, W2, wsw);
  dim3 grid(256, 16);
  fbpinn_main<<<grid, 256, 0, stream>>>(x, W0, b0, b1, b2, W3, b3, xmins, xmaxs, wsw, out);
}

// Round 3
// 235.772 us; speedup vs baseline: 1.7797x; 1.7797x over previous
//
#include <hip/hip_runtime.h>
#include <stdint.h>

#define TWF 0.2f
#define PI_F 3.14159265358979f
#define NPTS 16384

typedef __attribute__((ext_vector_type(8))) short short8;
typedef __attribute__((ext_vector_type(4))) float floatx4;

__device__ __forceinline__ short f2bf(float f){
  unsigned u = __float_as_uint(f);
  u += 0x7fff + ((u >> 16) & 1);           // round-to-nearest-even
  return (short)(u >> 16);
}
__device__ __forceinline__ float bf2f(short s){
  return __uint_as_float(((unsigned)(unsigned short)s) << 16);
}
// tanh(x) = 1 - 2/(exp2(2*log2e*x)+1); exact at +/-inf, 5 VALU (2 transcendental)
__device__ __forceinline__ float fast_tanh(float x){
  float e = __builtin_amdgcn_exp2f(x * 2.885390082f);
  float r = __builtin_amdgcn_rcpf(e + 1.f);
  return fmaf(-2.f, r, 1.f);
}
// swizzled LDS index (in shorts) for h[m][j], m in [0,64), j in [0,256)
__device__ __forceinline__ int swz(int m, int j){
  return m * 256 + ((((j >> 3) ^ (m & 7)) << 3) | (j & 7));
}

// ws layout (bytes):
//   [0, 4M)          : bf16-swizzled W1/W2
//   [4M, 4M+256)     : counts[16]
//   [4M+256, 5M+256) : ilist[16][16384]
//   [5M+256, 6M+256) : wlist[16][16384]
#define WS_W      0
#define WS_CNT    (4u<<20)
#define WS_ILIST  ((4u<<20) + 256u)
#define WS_WLIST  ((5u<<20) + 256u)

// Convert W1/W2 (f32 [16][256][256]) to bf16 in B-fragment lane order.
__global__ __launch_bounds__(256) void prep_weights(const float* __restrict__ W1,
                                                    const float* __restrict__ W2,
                                                    short* __restrict__ dst){
  int gid = blockIdx.x * 256 + threadIdx.x;   // 2*16*8*16*64 = 262144 total
  int lane = gid & 63; int rest = gid >> 6;
  int jt = rest & 15; rest >>= 4;
  int ks = rest & 7;  rest >>= 3;
  int k  = rest & 15; int mat = rest >> 4;
  const float* W = mat ? W2 : W1;
  int j   = jt * 16 + (lane & 15);
  int kk0 = ks * 32 + (lane >> 4) * 8;
  short8 v;
  #pragma unroll
  for (int jj = 0; jj < 8; jj++)
    v[jj] = f2bf(W[k * 65536 + (kk0 + jj) * 256 + j]);
  *(short8*)(dst + (size_t)gid * 8) = v;
}

// Phase 1: per-point window weights for all 16 k; compact indices of active
// (w>0) points into per-k lists via wave-aggregated atomics.
__global__ __launch_bounds__(256) void build_lists(
    const float* __restrict__ x, const float* __restrict__ xmins,
    const float* __restrict__ xmaxs, int* __restrict__ counts,
    int* __restrict__ ilist, float* __restrict__ wlist){
  int gid = blockIdx.x * 256 + threadIdx.x;   // one thread per point
  int lane = threadIdx.x & 63;
  float px = x[gid * 2 + 0], py = x[gid * 2 + 1];
  float wr[16]; float sum = 0.f;
  #pragma unroll
  for (int k = 0; k < 16; k++){
    float w = 1.f;
    #pragma unroll
    for (int d = 0; d < 2; d++){
      float xv = d ? py : px;
      float mn = xmins[k * 2 + d], mx = xmaxs[k * 2 + d];
      float tl = fminf(fmaxf((xv - (mn - TWF)) * (1.f / (2.f * TWF)), 0.f), 1.f);
      float tr = fminf(fmaxf(((mx + TWF) - xv) * (1.f / (2.f * TWF)), 0.f), 1.f);
      w *= 0.25f * (1.f - __cosf(PI_F * tl)) * (1.f - __cosf(PI_F * tr));
    }
    wr[k] = w; sum += w;
  }
  float inv = 1.f / (sum + 1e-9f);
  #pragma unroll 1
  for (int k = 0; k < 16; k++){
    bool act = wr[k] > 0.f;
    unsigned long long mask = __ballot(act);
    int base = 0;
    if (lane == 0) base = atomicAdd(&counts[k], (int)__popcll(mask));
    base = __shfl(base, 0);
    if (act){
      int pos = base + (int)__popcll(mask & ((1ull << lane) - 1ull));
      ilist[k * NPTS + pos] = gid;
      wlist[k * NPTS + pos] = wr[k] * inv;
    }
  }
}

__global__ __launch_bounds__(256) void fbpinn_main(
    const float* __restrict__ x,  const float* __restrict__ W0, const float* __restrict__ b0,
    const float* __restrict__ b1, const float* __restrict__ b2,
    const float* __restrict__ W3, const float* __restrict__ b3,
    const float* __restrict__ xmins, const float* __restrict__ xmaxs,
    const short* __restrict__ wsw, const int* __restrict__ counts,
    const int* __restrict__ ilist, const float* __restrict__ wlist,
    float* __restrict__ out)
{
  const int k   = blockIdx.y;
  const int cnt = counts[k];
  if ((int)blockIdx.x * 64 >= cnt) return;   // uniform early-exit (before barriers)

  __shared__ short lds_h[64 * 256];   // 32 KB, swizzled bf16 h tile
  __shared__ float s_xn[64 * 2];
  __shared__ float s_win[64];
  __shared__ int   s_pidx[64];
  __shared__ float s_w3[256];

  const int t    = threadIdx.x;
  const int base = blockIdx.x * 64;
  const int lane = t & 63;
  const int wave = t >> 6;
  const int col  = lane & 15;
  const int quad = lane >> 4;

  // ---- stage 1: gather compacted points, normalize, stage W3 ----
  s_w3[t] = W3[k * 256 + t];
  if (t < 64){
    int gi = base + t;
    bool valid = gi < cnt;
    int pidx = valid ? ilist[k * NPTS + gi] : 0;
    float w  = valid ? wlist[k * NPTS + gi] : 0.f;
    s_pidx[t] = pidx;
    s_win[t]  = w;
    float px = x[pidx * 2 + 0], py = x[pidx * 2 + 1];
    float cx = (xmins[k * 2 + 0] + xmaxs[k * 2 + 0]) * 0.5f;
    float cy = (xmins[k * 2 + 1] + xmaxs[k * 2 + 1]) * 0.5f;
    float sx = fmaxf((xmaxs[k * 2 + 0] - xmins[k * 2 + 0]) * 0.5f, 1e-9f);
    float sy = fmaxf((xmaxs[k * 2 + 1] - xmins[k * 2 + 1]) * 0.5f, 1e-9f);
    s_xn[t * 2 + 0] = (px - cx) / sx;
    s_xn[t * 2 + 1] = (py - cy) / sy;
  }
  __syncthreads();

  // ---- layer 0 (D=2 -> 256), f32 vector, thread t owns hidden unit j=t ----
  {
    float w00 = W0[k * 512 + t];
    float w01 = W0[k * 512 + 256 + t];
    float bb  = b0[k * 256 + t];
    #pragma unroll 4
    for (int m = 0; m < 64; m++){
      float v = fast_tanh(fmaf(s_xn[m * 2], w00, fmaf(s_xn[m * 2 + 1], w01, bb)));
      lds_h[swz(m, t)] = f2bf(v);
    }
  }
  __syncthreads();

  // ---- layers 1,2: 64x256x256 bf16 MFMA; wave owns j-range [wave*64, wave*64+64) ----
  #pragma unroll 1
  for (int layer = 0; layer < 2; layer++){
    const short8* wp = (const short8*)(wsw + (size_t)layer * 1048576);
    const float*  bp = layer ? b2 : b1;
    floatx4 acc[4][4];
    #pragma unroll
    for (int a = 0; a < 4; a++)
      #pragma unroll
      for (int b = 0; b < 4; b++)
        acc[a][b] = (floatx4){0.f, 0.f, 0.f, 0.f};

    #pragma unroll 2
    for (int ks = 0; ks < 8; ks++){
      short8 bfr[4], afr[4];
      #pragma unroll
      for (int jtl = 0; jtl < 4; jtl++)
        bfr[jtl] = wp[((size_t)(k * 8 + ks) * 16 + (wave * 4 + jtl)) * 64 + lane];
      #pragma unroll
      for (int mt = 0; mt < 4; mt++){
        int m   = mt * 16 + col;                 // A: m = lane&15
        int pos = (ks * 4 + quad) ^ (m & 7);     // A: k-chunk = quad
        afr[mt] = *(const short8*)&lds_h[m * 256 + pos * 8];
      }
      #pragma unroll
      for (int mt = 0; mt < 4; mt++)
        #pragma unroll
        for (int jtl = 0; jtl < 4; jtl++)
          acc[mt][jtl] = __builtin_amdgcn_mfma_f32_16x16x32_bf16(afr[mt], bfr[jtl], acc[mt][jtl], 0, 0, 0);
    }
    __syncthreads();   // all reads of h done before overwrite

    #pragma unroll
    for (int jtl = 0; jtl < 4; jtl++){
      int j = (wave * 4 + jtl) * 16 + col;       // D: col = lane&15
      float bb = bp[k * 256 + j];
      #pragma unroll
      for (int mt = 0; mt < 4; mt++){
        #pragma unroll
        for (int r = 0; r < 4; r++){
          int m = mt * 16 + quad * 4 + r;        // D: row = quad*4 + r
          float v = fast_tanh(acc[mt][jtl][r] + bb);
          lds_h[swz(m, j)] = f2bf(v);
        }
      }
    }
    __syncthreads();
  }

  // ---- layer 3 (256 -> 1) + window-weighted scatter ----
  {
    int m = t >> 2, q = t & 3;     // 4 threads per point
    float dot = 0.f;
    #pragma unroll
    for (int cc = 0; cc < 8; cc++){
      int ci  = q * 8 + cc;
      int pos = ci ^ (m & 7);
      short8 hv = *(const short8*)&lds_h[m * 256 + pos * 8];
      #pragma unroll
      for (int jj = 0; jj < 8; jj++)
        dot = fmaf(bf2f(hv[jj]), s_w3[ci * 8 + jj], dot);
    }
    dot += __shfl_xor(dot, 1);
    dot += __shfl_xor(dot, 2);
    if (q == 0 && s_win[m] != 0.f)
      atomicAdd(&out[s_pidx[m]], s_win[m] * (dot + b3[k]));
  }
}

extern "C" void kernel_launch(void* const* d_in, const int* in_sizes, int n_in,
                              void* d_out, int out_size, void* d_ws, size_t ws_size,
                              hipStream_t stream){
  const float* x     = (const float*)d_in[0];
  const float* W0    = (const float*)d_in[1];
  const float* b0    = (const float*)d_in[2];
  const float* W1    = (const float*)d_in[3];
  const float* b1    = (const float*)d_in[4];
  const float* W2    = (const float*)d_in[5];
  const float* b2    = (const float*)d_in[6];
  const float* W3    = (const float*)d_in[7];
  const float* b3    = (const float*)d_in[8];
  const float* xmins = (const float*)d_in[9];
  const float* xmaxs = (const float*)d_in[10];
  float* out = (float*)d_out;

  char* ws = (char*)d_ws;                     // needs ~6.3 MB
  short* wsw   = (short*)(ws + WS_W);
  int*   cnts  = (int*)  (ws + WS_CNT);
  int*   ilist = (int*)  (ws + WS_ILIST);
  float* wlist = (float*)(ws + WS_WLIST);

  (void)hipMemsetAsync(d_out, 0, (size_t)out_size * sizeof(float), stream);
  (void)hipMemsetAsync(cnts, 0, 256, stream);
  prep_weights<<<1024, 256, 0, stream>>>(W1, W2, wsw);
  build_lists<<<NPTS / 256, 256, 0, stream>>>(x, xmins, xmaxs, cnts, ilist, wlist);
  dim3 grid(256, 16);
  fbpinn_main<<<grid, 256, 0, stream>>>(x, W0, b0, b1, b2, W3, b3, xmins, xmaxs,
                                        wsw, cnts, ilist, wlist, out);
}

// Round 4
// 176.697 us; speedup vs baseline: 2.3747x; 1.3343x over previous
//
#include <hip/hip_runtime.h>
#include <stdint.h>

#define TWF 0.2f
#define NPTS 16384

typedef __attribute__((ext_vector_type(8))) short short8;
typedef __attribute__((ext_vector_type(4))) float floatx4;

__device__ __forceinline__ short f2bf(float f){
  unsigned u = __float_as_uint(f);
  u += 0x7fff + ((u >> 16) & 1);           // round-to-nearest-even
  return (short)(u >> 16);
}
__device__ __forceinline__ float bf2f(short s){
  return __uint_as_float(((unsigned)(unsigned short)s) << 16);
}
// tanh(x) = 1 - 2/(exp2(2*log2e*x)+1); exact at +/-inf
__device__ __forceinline__ float fast_tanh(float x){
  float e = __builtin_amdgcn_exp2f(x * 2.885390082f);
  float r = __builtin_amdgcn_rcpf(e + 1.f);
  return fmaf(-2.f, r, 1.f);
}
// cos(pi*t) via v_cos (revolutions): cos(2*pi*(t/2))
__device__ __forceinline__ float cospi_t(float t){
  return __builtin_amdgcn_cosf(t * 0.5f);
}
// swizzled LDS index (in shorts) for h[m][j], m in [0,64), j in [0,256)
__device__ __forceinline__ int swz(int m, int j){
  return m * 256 + ((((j >> 3) ^ (m & 7)) << 3) | (j & 7));
}

// ws layout (bytes):
//   [0, 4M)          : bf16-swizzled W1/W2
//   [4M, 4M+256)     : counts[16]
//   [4M+256, 5M+256) : ilist[16][16384]
//   [5M+256, 6M+256) : wlist[16][16384]
#define WS_W      0
#define WS_CNT    (4u<<20)
#define WS_ILIST  ((4u<<20) + 256u)
#define WS_WLIST  ((5u<<20) + 256u)

// Fused: blocks [0,1024) convert W1/W2 to bf16 B-fragment order;
// blocks [1024,1088) build per-k compacted point lists.
__global__ __launch_bounds__(256) void prep_fused(
    const float* __restrict__ W1, const float* __restrict__ W2,
    const float* __restrict__ x,  const float* __restrict__ xmins,
    const float* __restrict__ xmaxs, short* __restrict__ dst,
    int* __restrict__ counts, int* __restrict__ ilist, float* __restrict__ wlist){
  if (blockIdx.x < 1024){
    int gid = blockIdx.x * 256 + threadIdx.x;   // 2*16*8*16*64 = 262144 total
    int lane = gid & 63; int rest = gid >> 6;
    int jt = rest & 15; rest >>= 4;
    int ks = rest & 7;  rest >>= 3;
    int k  = rest & 15; int mat = rest >> 4;
    const float* W = mat ? W2 : W1;
    int j   = jt * 16 + (lane & 15);
    int kk0 = ks * 32 + (lane >> 4) * 8;
    short8 v;
    #pragma unroll
    for (int jj = 0; jj < 8; jj++)
      v[jj] = f2bf(W[k * 65536 + (kk0 + jj) * 256 + j]);
    *(short8*)(dst + (size_t)gid * 8) = v;
  } else {
    int gid  = (blockIdx.x - 1024) * 256 + threadIdx.x;  // one thread per point
    int lane = threadIdx.x & 63;
    int wsh  = (gid >> 6) & 15;                          // per-wave k stagger
    float px = x[gid * 2 + 0], py = x[gid * 2 + 1];
    float wr[16]; float sum = 0.f;
    #pragma unroll
    for (int k = 0; k < 16; k++){
      float w = 1.f;
      #pragma unroll
      for (int d = 0; d < 2; d++){
        float xv = d ? py : px;
        float mn = xmins[k * 2 + d], mx = xmaxs[k * 2 + d];
        float tl = fminf(fmaxf((xv - (mn - TWF)) * (1.f / (2.f * TWF)), 0.f), 1.f);
        float tr = fminf(fmaxf(((mx + TWF) - xv) * (1.f / (2.f * TWF)), 0.f), 1.f);
        w *= 0.25f * (1.f - cospi_t(tl)) * (1.f - cospi_t(tr));
      }
      wr[k] = w; sum += w;
    }
    float inv = 1.f / (sum + 1e-9f);
    #pragma unroll 1
    for (int kk = 0; kk < 16; kk++){
      int k = (kk + wsh) & 15;                           // spread atomic contention
      bool act = wr[k] > 0.f;
      unsigned long long mask = __ballot(act);
      int base = 0;
      if (lane == 0) base = atomicAdd(&counts[k], (int)__popcll(mask));
      base = __shfl(base, 0);
      if (act){
        int pos = base + (int)__popcll(mask & ((1ull << lane) - 1ull));
        ilist[k * NPTS + pos] = gid;
        wlist[k * NPTS + pos] = wr[k] * inv;
      }
    }
  }
}

__global__ __launch_bounds__(256, 3) void fbpinn_main(
    const float* __restrict__ x,  const float* __restrict__ W0, const float* __restrict__ b0,
    const float* __restrict__ b1, const float* __restrict__ b2,
    const float* __restrict__ W3, const float* __restrict__ b3,
    const float* __restrict__ xmins, const float* __restrict__ xmaxs,
    const short* __restrict__ wsw, const int* __restrict__ counts,
    const int* __restrict__ ilist, const float* __restrict__ wlist,
    float* __restrict__ out)
{
  __shared__ short lds_h[64 * 256];   // 32 KB, swizzled bf16 h tile
  __shared__ float s_xn[64 * 2];
  __shared__ float s_win[64];
  __shared__ int   s_pidx[64];
  __shared__ float s_w3[256];

  const int t    = threadIdx.x;
  const int lane = t & 63;
  const int wave = t >> 6;
  const int col  = lane & 15;
  const int quad = lane >> 4;

  // live-tile partition: prefix over per-k tile counts (uniform, ~16 scalar ops)
  int tb[17]; tb[0] = 0;
  #pragma unroll
  for (int kk = 0; kk < 16; kk++) tb[kk + 1] = tb[kk] + ((counts[kk] + 63) >> 6);
  const int total = tb[16];

  for (int tile = blockIdx.x; tile < total; tile += gridDim.x){
    int k = 0;
    #pragma unroll
    for (int kk = 1; kk < 16; kk++) k += (tile >= tb[kk]);
    const int base = (tile - tb[k]) * 64;
    const int cnt  = counts[k];

    __syncthreads();   // previous tile's layer-3 reads done before s_* overwrite

    // ---- stage 1: gather compacted points, normalize, stage W3 ----
    s_w3[t] = W3[k * 256 + t];
    if (t < 64){
      int gi = base + t;
      bool valid = gi < cnt;
      int pidx = valid ? ilist[k * NPTS + gi] : 0;
      float w  = valid ? wlist[k * NPTS + gi] : 0.f;
      s_pidx[t] = pidx;
      s_win[t]  = w;
      float px = x[pidx * 2 + 0], py = x[pidx * 2 + 1];
      float cx = (xmins[k * 2 + 0] + xmaxs[k * 2 + 0]) * 0.5f;
      float cy = (xmins[k * 2 + 1] + xmaxs[k * 2 + 1]) * 0.5f;
      float sx = fmaxf((xmaxs[k * 2 + 0] - xmins[k * 2 + 0]) * 0.5f, 1e-9f);
      float sy = fmaxf((xmaxs[k * 2 + 1] - xmins[k * 2 + 1]) * 0.5f, 1e-9f);
      s_xn[t * 2 + 0] = (px - cx) / sx;
      s_xn[t * 2 + 1] = (py - cy) / sy;
    }
    __syncthreads();

    // ---- layer 0 (D=2 -> 256), f32 vector, thread t owns hidden unit j=t ----
    {
      float w00 = W0[k * 512 + t];
      float w01 = W0[k * 512 + 256 + t];
      float bb  = b0[k * 256 + t];
      #pragma unroll 4
      for (int m = 0; m < 64; m++){
        float v = fast_tanh(fmaf(s_xn[m * 2], w00, fmaf(s_xn[m * 2 + 1], w01, bb)));
        lds_h[swz(m, t)] = f2bf(v);
      }
    }
    __syncthreads();

    // ---- layers 1,2: 64x256x256 bf16 MFMA; wave owns j-range [wave*64, +64) ----
    #pragma unroll 1
    for (int layer = 0; layer < 2; layer++){
      const short8* wb = (const short8*)(wsw + (size_t)layer * 1048576)
                         + ((size_t)(k * 8) * 16 + wave * 4) * 64 + lane;
      const float*  bp = layer ? b2 : b1;
      floatx4 acc[4][4];
      #pragma unroll
      for (int a = 0; a < 4; a++)
        #pragma unroll
        for (int b = 0; b < 4; b++)
          acc[a][b] = (floatx4){0.f, 0.f, 0.f, 0.f};

      short8 bcur[4];
      #pragma unroll
      for (int jtl = 0; jtl < 4; jtl++) bcur[jtl] = wb[jtl * 64];

      #pragma unroll
      for (int ks = 0; ks < 8; ks++){
        short8 bnxt[4];
        if (ks < 7){
          #pragma unroll
          for (int jtl = 0; jtl < 4; jtl++)
            bnxt[jtl] = wb[(ks + 1) * 1024 + jtl * 64];   // prefetch next K-step
        }
        short8 afr[4];
        #pragma unroll
        for (int mt = 0; mt < 4; mt++){
          int m   = mt * 16 + col;                 // A: m = lane&15
          int pos = (ks * 4 + quad) ^ (m & 7);     // A: k-chunk = quad
          afr[mt] = *(const short8*)&lds_h[m * 256 + pos * 8];
        }
        #pragma unroll
        for (int mt = 0; mt < 4; mt++)
          #pragma unroll
          for (int jtl = 0; jtl < 4; jtl++)
            acc[mt][jtl] = __builtin_amdgcn_mfma_f32_16x16x32_bf16(afr[mt], bcur[jtl], acc[mt][jtl], 0, 0, 0);
        if (ks < 7){
          #pragma unroll
          for (int jtl = 0; jtl < 4; jtl++) bcur[jtl] = bnxt[jtl];
        }
      }
      __syncthreads();   // all reads of h done before overwrite

      #pragma unroll
      for (int jtl = 0; jtl < 4; jtl++){
        int j = (wave * 4 + jtl) * 16 + col;       // D: col = lane&15
        float bb = bp[k * 256 + j];
        #pragma unroll
        for (int mt = 0; mt < 4; mt++){
          #pragma unroll
          for (int r = 0; r < 4; r++){
            int m = mt * 16 + quad * 4 + r;        // D: row = quad*4 + r
            float v = fast_tanh(acc[mt][jtl][r] + bb);
            lds_h[swz(m, j)] = f2bf(v);
          }
        }
      }
      __syncthreads();
    }

    // ---- layer 3 (256 -> 1) + window-weighted scatter ----
    {
      int m = t >> 2, q = t & 3;     // 4 threads per point
      float dot = 0.f;
      #pragma unroll
      for (int cc = 0; cc < 8; cc++){
        int ci  = q * 8 + cc;
        int pos = ci ^ (m & 7);
        short8 hv = *(const short8*)&lds_h[m * 256 + pos * 8];
        #pragma unroll
        for (int jj = 0; jj < 8; jj++)
          dot = fmaf(bf2f(hv[jj]), s_w3[ci * 8 + jj], dot);
      }
      dot += __shfl_xor(dot, 1);
      dot += __shfl_xor(dot, 2);
      if (q == 0 && s_win[m] != 0.f)
        atomicAdd(&out[s_pidx[m]], s_win[m] * (dot + b3[k]));
    }
  }
}

extern "C" void kernel_launch(void* const* d_in, const int* in_sizes, int n_in,
                              void* d_out, int out_size, void* d_ws, size_t ws_size,
                              hipStream_t stream){
  const float* x     = (const float*)d_in[0];
  const float* W0    = (const float*)d_in[1];
  const float* b0    = (const float*)d_in[2];
  const float* W1    = (const float*)d_in[3];
  const float* b1    = (const float*)d_in[4];
  const float* W2    = (const float*)d_in[5];
  const float* b2    = (const float*)d_in[6];
  const float* W3    = (const float*)d_in[7];
  const float* b3    = (const float*)d_in[8];
  const float* xmins = (const float*)d_in[9];
  const float* xmaxs = (const float*)d_in[10];
  float* out = (float*)d_out;

  char* ws = (char*)d_ws;                     // needs ~6.3 MB
  short* wsw   = (short*)(ws + WS_W);
  int*   cnts  = (int*)  (ws + WS_CNT);
  int*   ilist = (int*)  (ws + WS_ILIST);
  float* wlist = (float*)(ws + WS_WLIST);

  (void)hipMemsetAsync(d_out, 0, (size_t)out_size * sizeof(float), stream);
  (void)hipMemsetAsync(cnts, 0, 256, stream);
  prep_fused<<<1024 + NPTS / 256, 256, 0, stream>>>(W1, W2, x, xmins, xmaxs,
                                                    wsw, cnts, ilist, wlist);
  fbpinn_main<<<1024, 256, 0, stream>>>(x, W0, b0, b1, b2, W3, b3, xmins, xmaxs,
                                        wsw, cnts, ilist, wlist, out);
}

// Round 5
// 155.307 us; speedup vs baseline: 2.7017x; 1.1377x over previous
//
#include <hip/hip_runtime.h>
#include <stdint.h>

#define TWF 0.2f
#define NPTS 16384

typedef __attribute__((ext_vector_type(8))) short short8;
typedef __attribute__((ext_vector_type(4))) float floatx4;

__device__ __forceinline__ short f2bf(float f){
  unsigned u = __float_as_uint(f);
  u += 0x7fff + ((u >> 16) & 1);           // round-to-nearest-even
  return (short)(u >> 16);
}
__device__ __forceinline__ float bf2f(short s){
  return __uint_as_float(((unsigned)(unsigned short)s) << 16);
}
// tanh(x) = 1 - 2/(exp2(2*log2e*x)+1); exact at +/-inf
__device__ __forceinline__ float fast_tanh(float x){
  float e = __builtin_amdgcn_exp2f(x * 2.885390082f);
  float r = __builtin_amdgcn_rcpf(e + 1.f);
  return fmaf(-2.f, r, 1.f);
}
// cos(pi*t) via v_cos (revolutions)
__device__ __forceinline__ float cospi_t(float t){
  return __builtin_amdgcn_cosf(t * 0.5f);
}
// swizzled LDS index (in shorts) for h[m][j], m in [0,64), j in [0,256)
__device__ __forceinline__ int swz(int m, int j){
  return m * 256 + ((((j >> 3) ^ (m & 7)) << 3) | (j & 7));
}

// ws layout (bytes):
//   [0, 4M)            : bf16-swizzled W1/W2
//   [4M, 4M+4K)        : counts[16], 128B stride (one L2 line each)
//   [4M+4K, 5M+4K)     : ilist[16][16384]
//   [5M+4K, 6M+4K)     : wlist[16][16384]
#define WS_W      0
#define WS_CNT    (4u<<20)
#define WS_ILIST  ((4u<<20) + 4096u)
#define WS_WLIST  ((5u<<20) + 4096u)
#define CNT(k)    counts[(k) * 32]

// Fused: blocks [0,1024) convert W1/W2 to bf16 B-fragment order;
// blocks [1024,1088) zero `out` and build per-k compacted point lists
// (block-aggregated atomics: 1 atomicAdd per block per k, padded lines).
__global__ __launch_bounds__(256) void prep_fused(
    const float* __restrict__ W1, const float* __restrict__ W2,
    const float* __restrict__ x,  const float* __restrict__ xmins,
    const float* __restrict__ xmaxs, short* __restrict__ dst,
    int* __restrict__ counts, int* __restrict__ ilist, float* __restrict__ wlist,
    float* __restrict__ out){
  if (blockIdx.x < 1024){
    int gid = blockIdx.x * 256 + threadIdx.x;   // 2*16*8*16*64 = 262144 total
    int lane = gid & 63; int rest = gid >> 6;
    int jt = rest & 15; rest >>= 4;
    int ks = rest & 7;  rest >>= 3;
    int k  = rest & 15; int mat = rest >> 4;
    const float* W = mat ? W2 : W1;
    int j   = jt * 16 + (lane & 15);
    int kk0 = ks * 32 + (lane >> 4) * 8;
    short8 v;
    #pragma unroll
    for (int jj = 0; jj < 8; jj++)
      v[jj] = f2bf(W[k * 65536 + (kk0 + jj) * 256 + j]);
    *(short8*)(dst + (size_t)gid * 8) = v;
  } else {
    __shared__ int s_wcnt[4];
    __shared__ int s_base;
    int gid  = (blockIdx.x - 1024) * 256 + threadIdx.x;  // one thread per point
    int t    = threadIdx.x;
    int lane = t & 63, wave = t >> 6;
    out[gid] = 0.f;                                      // fold memset(out)
    float px = x[gid * 2 + 0], py = x[gid * 2 + 1];
    float wr[16]; float sum = 0.f;
    #pragma unroll
    for (int k = 0; k < 16; k++){
      float w = 1.f;
      #pragma unroll
      for (int d = 0; d < 2; d++){
        float xv = d ? py : px;
        float mn = xmins[k * 2 + d], mx = xmaxs[k * 2 + d];
        float tl = fminf(fmaxf((xv - (mn - TWF)) * (1.f / (2.f * TWF)), 0.f), 1.f);
        float tr = fminf(fmaxf(((mx + TWF) - xv) * (1.f / (2.f * TWF)), 0.f), 1.f);
        w *= 0.25f * (1.f - cospi_t(tl)) * (1.f - cospi_t(tr));
      }
      wr[k] = w; sum += w;
    }
    float inv = 1.f / (sum + 1e-9f);
    #pragma unroll 1
    for (int kk = 0; kk < 16; kk++){
      int k = (kk + blockIdx.x) & 15;              // spread initial line load
      bool act = wr[k] > 0.f;
      unsigned long long mask = __ballot(act);
      if (lane == 0) s_wcnt[wave] = (int)__popcll(mask);
      __syncthreads();
      int tot = s_wcnt[0] + s_wcnt[1] + s_wcnt[2] + s_wcnt[3];
      int wpre = 0;
      #pragma unroll
      for (int w = 0; w < 4; w++) wpre += (w < wave) ? s_wcnt[w] : 0;
      if (t == 0) s_base = atomicAdd(&CNT(k), tot);
      __syncthreads();
      if (act){
        int pos = s_base + wpre + (int)__popcll(mask & ((1ull << lane) - 1ull));
        ilist[k * NPTS + pos] = gid;
        wlist[k * NPTS + pos] = wr[k] * inv;
      }
    }
  }
}

__global__ __launch_bounds__(256, 3) void fbpinn_main(
    const float* __restrict__ x,  const float* __restrict__ W0, const float* __restrict__ b0,
    const float* __restrict__ b1, const float* __restrict__ b2,
    const float* __restrict__ W3, const float* __restrict__ b3,
    const float* __restrict__ xmins, const float* __restrict__ xmaxs,
    const short* __restrict__ wsw, const int* __restrict__ counts,
    const int* __restrict__ ilist, const float* __restrict__ wlist,
    float* __restrict__ out)
{
  __shared__ short lds_h[64 * 256];   // 32 KB, swizzled bf16 h tile
  __shared__ float s_xn[64 * 2];
  __shared__ float s_win[64];
  __shared__ int   s_pidx[64];
  __shared__ float s_w3[256];
  __shared__ float s_w0[512];

  const int t    = threadIdx.x;
  const int lane = t & 63;
  const int wave = t >> 6;
  const int col  = lane & 15;
  const int quad = lane >> 4;

  // live-tile partition: prefix over per-k tile counts
  int tb[17]; tb[0] = 0;
  #pragma unroll
  for (int kk = 0; kk < 16; kk++) tb[kk + 1] = tb[kk] + ((CNT(kk) + 63) >> 6);
  const int total = tb[16];

  for (int tile = blockIdx.x; tile < total; tile += gridDim.x){
    int k = 0;
    #pragma unroll
    for (int kk = 1; kk < 16; kk++) k += (tile >= tb[kk]);
    const int base = (tile - tb[k]) * 64;
    const int cnt  = CNT(k);

    __syncthreads();   // previous tile's layer-3 reads done before s_* overwrite

    // ---- stage: gather compacted points, normalize, stage W0/W3 ----
    s_w3[t] = W3[k * 256 + t];
    s_w0[t] = W0[k * 512 + t];
    s_w0[256 + t] = W0[k * 512 + 256 + t];
    if (t < 64){
      int gi = base + t;
      bool valid = gi < cnt;
      int pidx = valid ? ilist[k * NPTS + gi] : 0;
      float w  = valid ? wlist[k * NPTS + gi] : 0.f;
      s_pidx[t] = pidx;
      s_win[t]  = w;
      float px = x[pidx * 2 + 0], py = x[pidx * 2 + 1];
      float cx = (xmins[k * 2 + 0] + xmaxs[k * 2 + 0]) * 0.5f;
      float cy = (xmins[k * 2 + 1] + xmaxs[k * 2 + 1]) * 0.5f;
      float sx = fmaxf((xmaxs[k * 2 + 0] - xmins[k * 2 + 0]) * 0.5f, 1e-9f);
      float sy = fmaxf((xmaxs[k * 2 + 1] - xmins[k * 2 + 1]) * 0.5f, 1e-9f);
      s_xn[t * 2 + 0] = (px - cx) / sx;
      s_xn[t * 2 + 1] = (py - cy) / sy;
    }
    __syncthreads();

    // ---- layer 0 (D=2 -> 256) as one MFMA K-step (K padded 2->32) ----
    {
      short8 bfr[4], afr[4];
      #pragma unroll
      for (int jtl = 0; jtl < 4; jtl++){
        int j = (wave * 4 + jtl) * 16 + col;
        short8 b;
        #pragma unroll
        for (int i = 0; i < 8; i++) b[i] = 0;
        b[0] = (quad == 0) ? f2bf(s_w0[j])       : (short)0;
        b[1] = (quad == 0) ? f2bf(s_w0[256 + j]) : (short)0;
        bfr[jtl] = b;
      }
      #pragma unroll
      for (int mt = 0; mt < 4; mt++){
        int m = mt * 16 + col;
        short8 a;
        #pragma unroll
        for (int i = 0; i < 8; i++) a[i] = 0;
        a[0] = (quad == 0) ? f2bf(s_xn[m * 2 + 0]) : (short)0;
        a[1] = (quad == 0) ? f2bf(s_xn[m * 2 + 1]) : (short)0;
        afr[mt] = a;
      }
      floatx4 acc[4][4];
      #pragma unroll
      for (int a = 0; a < 4; a++)
        #pragma unroll
        for (int b = 0; b < 4; b++)
          acc[a][b] = (floatx4){0.f, 0.f, 0.f, 0.f};
      #pragma unroll
      for (int mt = 0; mt < 4; mt++)
        #pragma unroll
        for (int jtl = 0; jtl < 4; jtl++)
          acc[mt][jtl] = __builtin_amdgcn_mfma_f32_16x16x32_bf16(afr[mt], bfr[jtl], acc[mt][jtl], 0, 0, 0);
      #pragma unroll
      for (int jtl = 0; jtl < 4; jtl++){
        int j = (wave * 4 + jtl) * 16 + col;
        float bb = b0[k * 256 + j];
        #pragma unroll
        for (int mt = 0; mt < 4; mt++){
          #pragma unroll
          for (int r = 0; r < 4; r++){
            int m = mt * 16 + quad * 4 + r;
            lds_h[swz(m, j)] = f2bf(fast_tanh(acc[mt][jtl][r] + bb));
          }
        }
      }
      __syncthreads();
    }

    // ---- layers 1,2: 64x256x256 bf16 MFMA; wave owns j-range [wave*64, +64) ----
    #pragma unroll 1
    for (int layer = 0; layer < 2; layer++){
      const short8* wb = (const short8*)(wsw + (size_t)layer * 1048576)
                         + ((size_t)(k * 8) * 16 + wave * 4) * 64 + lane;
      const float*  bp = layer ? b2 : b1;
      floatx4 acc[4][4];
      #pragma unroll
      for (int a = 0; a < 4; a++)
        #pragma unroll
        for (int b = 0; b < 4; b++)
          acc[a][b] = (floatx4){0.f, 0.f, 0.f, 0.f};

      short8 bcur[4];
      #pragma unroll
      for (int jtl = 0; jtl < 4; jtl++) bcur[jtl] = wb[jtl * 64];

      #pragma unroll
      for (int ks = 0; ks < 8; ks++){
        short8 bnxt[4];
        if (ks < 7){
          #pragma unroll
          for (int jtl = 0; jtl < 4; jtl++)
            bnxt[jtl] = wb[(ks + 1) * 1024 + jtl * 64];   // prefetch next K-step
        }
        short8 afr[4];
        #pragma unroll
        for (int mt = 0; mt < 4; mt++){
          int m   = mt * 16 + col;                 // A: m = lane&15
          int pos = (ks * 4 + quad) ^ (m & 7);     // A: k-chunk = quad
          afr[mt] = *(const short8*)&lds_h[m * 256 + pos * 8];
        }
        #pragma unroll
        for (int mt = 0; mt < 4; mt++)
          #pragma unroll
          for (int jtl = 0; jtl < 4; jtl++)
            acc[mt][jtl] = __builtin_amdgcn_mfma_f32_16x16x32_bf16(afr[mt], bcur[jtl], acc[mt][jtl], 0, 0, 0);
        if (ks < 7){
          #pragma unroll
          for (int jtl = 0; jtl < 4; jtl++) bcur[jtl] = bnxt[jtl];
        }
      }
      __syncthreads();   // all reads of h done before overwrite

      #pragma unroll
      for (int jtl = 0; jtl < 4; jtl++){
        int j = (wave * 4 + jtl) * 16 + col;       // D: col = lane&15
        float bb = bp[k * 256 + j];
        #pragma unroll
        for (int mt = 0; mt < 4; mt++){
          #pragma unroll
          for (int r = 0; r < 4; r++){
            int m = mt * 16 + quad * 4 + r;        // D: row = quad*4 + r
            lds_h[swz(m, j)] = f2bf(fast_tanh(acc[mt][jtl][r] + bb));
          }
        }
      }
      __syncthreads();
    }

    // ---- layer 3 (256 -> 1) + window-weighted scatter ----
    {
      int m = t >> 2, q = t & 3;     // 4 threads per point
      float dot = 0.f;
      #pragma unroll
      for (int cc = 0; cc < 8; cc++){
        int ci  = q * 8 + cc;
        int pos = ci ^ (m & 7);
        short8 hv = *(const short8*)&lds_h[m * 256 + pos * 8];
        #pragma unroll
        for (int jj = 0; jj < 8; jj++)
          dot = fmaf(bf2f(hv[jj]), s_w3[ci * 8 + jj], dot);
      }
      dot += __shfl_xor(dot, 1);
      dot += __shfl_xor(dot, 2);
      if (q == 0 && s_win[m] != 0.f)
        atomicAdd(&out[s_pidx[m]], s_win[m] * (dot + b3[k]));
    }
  }
}

extern "C" void kernel_launch(void* const* d_in, const int* in_sizes, int n_in,
                              void* d_out, int out_size, void* d_ws, size_t ws_size,
                              hipStream_t stream){
  const float* x     = (const float*)d_in[0];
  const float* W0    = (const float*)d_in[1];
  const float* b0    = (const float*)d_in[2];
  const float* W1    = (const float*)d_in[3];
  const float* b1    = (const float*)d_in[4];
  const float* W2    = (const float*)d_in[5];
  const float* b2    = (const float*)d_in[6];
  const float* W3    = (const float*)d_in[7];
  const float* b3    = (const float*)d_in[8];
  const float* xmins = (const float*)d_in[9];
  const float* xmaxs = (const float*)d_in[10];
  float* out = (float*)d_out;

  char* ws = (char*)d_ws;                     // needs ~6.3 MB
  short* wsw   = (short*)(ws + WS_W);
  int*   cnts  = (int*)  (ws + WS_CNT);
  int*   ilist = (int*)  (ws + WS_ILIST);
  float* wlist = (float*)(ws + WS_WLIST);

  (void)hipMemsetAsync(cnts, 0, 4096, stream);
  prep_fused<<<1024 + NPTS / 256, 256, 0, stream>>>(W1, W2, x, xmins, xmaxs,
                                                    wsw, cnts, ilist, wlist, out);
  fbpinn_main<<<640, 256, 0, stream>>>(x, W0, b0, b1, b2, W3, b3, xmins, xmaxs,
                                       wsw, cnts, ilist, wlist, out);
}